// Round 3
// baseline (412.138 us; speedup 1.0000x reference)
//
#include <hip/hip_runtime.h>
#include <hip/hip_bf16.h>

typedef __bf16 bf16x8 __attribute__((ext_vector_type(8)));
typedef float  f32x4  __attribute__((ext_vector_type(4)));

#define MFMA16(A,B,C) __builtin_amdgcn_mfma_f32_16x16x32_bf16((A),(B),(C),0,0,0)

constexpr int NB = 8, NN = 8192, KK = 16;
constexpr size_t WS_NEEDED = 75776;

// ws layout (bytes):
//   w3f : [16 nb][2 ks][64 lane][8] bf16  -> 32768 B @ 0
//   w4f : [ 4 nb][8 kb][64 lane][8] bf16  -> 32768 B @ 32768
//   w2f : [ 4 nb][2 ks][64 lane][8] bf16  ->  8192 B @ 65536
//   W1f : [3][64] f32                     ->   768 B @ 73728
//   c1f : [64]  f32                       ->   256 B @ 74496
//   c3f : [256] f32                       ->  1024 B @ 74752

__global__ void prep_kernel(const float* __restrict__ W1, const float* __restrict__ b1,
                            const float* __restrict__ g1, const float* __restrict__ bt1,
                            const float* __restrict__ W2, const float* __restrict__ W3,
                            const float* __restrict__ b3, const float* __restrict__ g3,
                            const float* __restrict__ bt3, const float* __restrict__ W4,
                            unsigned char* __restrict__ ws)
{
    __bf16* w3f = (__bf16*)(ws);
    __bf16* w4f = (__bf16*)(ws + 32768);
    __bf16* w2f = (__bf16*)(ws + 65536);
    float*  W1f = (float*)(ws + 73728);
    float*  c1f = (float*)(ws + 74496);
    float*  c3f = (float*)(ws + 74752);

    const float inv = 1.0f / sqrtf(1.0f + 1e-3f);   // BN with init moving stats
    int t = blockIdx.x * 256 + threadIdx.x;

    if (t < 16384) {                    // W3 * s3 -> frag order
        int i = t & 7, lane = (t >> 3) & 63, r = t >> 9;
        int ks = r & 1, nb = r >> 1;
        int k = ks * 32 + (lane >> 4) * 8 + i;
        int n = nb * 16 + (lane & 15);
        w3f[t] = (__bf16)(W3[k * 256 + n] * (g3[n] * inv));
    } else if (t < 32768) {             // W4 / 8 -> frag order
        int u = t - 16384;
        int i = u & 7, lane = (u >> 3) & 63, r = u >> 9;
        int kb = r & 7, nb = r >> 3;
        int k = kb * 32 + (lane >> 4) * 8 + i;
        int n = nb * 16 + (lane & 15);
        w4f[u] = (__bf16)(W4[k * 64 + n] * 0.125f);
    } else if (t < 36864) {             // W2 -> frag order
        int u = t - 32768;
        int i = u & 7, lane = (u >> 3) & 63, r = u >> 9;
        int ks = r & 1, nb = r >> 1;
        int k = ks * 32 + (lane >> 4) * 8 + i;
        int n = nb * 16 + (lane & 15);
        w2f[u] = (__bf16)(W2[k * 64 + n]);
    } else if (t < 37056) {             // W1 * s1 (fp32)
        int u = t - 36864;              // u = d*64 + c
        int c = u & 63;
        W1f[u] = W1[u] * (g1[c] * inv);
    } else if (t < 37120) {             // c1f = b1*s1 + bt1
        int c = t - 37056;
        c1f[c] = b1[c] * (g1[c] * inv) + bt1[c];
    } else if (t < 37376) {             // c3f = b3*s3 + bt3
        int n = t - 37120;
        c3f[n] = b3[n] * (g3[n] * inv) + bt3[n];
    }
}

// One wave = 2 points (32 rows = 2x16 neighbor blocks). 4 waves/block, no barriers.
// __launch_bounds__(256,4): cap arch VGPR+AGPR at 128 -> 4 waves/SIMD, 4 blocks/CU
// (round-2 run at (256,2): AGPR allocation pushed arch regs ~184 -> only 2 blocks/CU, 22.7% occ).
__global__ __launch_bounds__(256, 4) void fused_kernel(
    const float* __restrict__ key, const float* __restrict__ query,
    const float* __restrict__ value, const float* __restrict__ pos,
    const int* __restrict__ idx, const float* __restrict__ b2,
    const float* __restrict__ b4, const unsigned char* __restrict__ ws,
    float* __restrict__ out)
{
    const __bf16* w3f = (const __bf16*)(ws);
    const __bf16* w4f = (const __bf16*)(ws + 32768);
    const __bf16* w2f = (const __bf16*)(ws + 65536);
    const float*  W1f = (const float*)(ws + 73728);
    const float*  c1f = (const float*)(ws + 74496);
    const float*  c3f = (const float*)(ws + 74752);

    __shared__ __attribute__((aligned(16))) __bf16 sX [4][2048];  // h, then X, then posem stash
    __shared__ __attribute__((aligned(16))) __bf16 sA1[4][2048];  // GEMM1 chunk bounce
    __shared__ __attribute__((aligned(16))) float  sPR[4][32][4]; // pos_rel per row
    __shared__ int sJ[4][32];                                      // neighbor idx per row

    const int wv   = threadIdx.x >> 6;
    const int lane = threadIdx.x & 63;
    const int lg   = lane >> 4;      // 16-lane group 0..3
    const int ln   = lane & 15;

    const int ptbase = blockIdx.x * 8 + wv * 2;  // global point of rb=0
    const int b  = ptbase >> 13;                 // / 8192
    const int n0 = ptbase & 8191;

    __bf16* X  = sX[wv];
    __bf16* A1 = sA1[wv];

    // ---------- Phase A: pos_rel, neighbor idx, h = relu(pos_rel @ W1f + c1f)
    if (lane < 32) {
        int p = lane >> 4, k = lane & 15;
        int n = n0 + p;
        int j = idx[(b * NN + n) * KK + k];
        sJ[wv][lane] = j;
        int pb = (b * NN + n) * 3, jb = (b * NN + j) * 3;
        sPR[wv][lane][0] = pos[pb + 0] - pos[jb + 0];
        sPR[wv][lane][1] = pos[pb + 1] - pos[jb + 1];
        sPR[wv][lane][2] = pos[pb + 2] - pos[jb + 2];
        sPR[wv][lane][3] = 0.f;
    }
    {
        // lane = output channel c
        float w0 = W1f[lane], w1 = W1f[64 + lane], w2c = W1f[128 + lane], cc1 = c1f[lane];
        for (int r = 0; r < 32; ++r) {
            float4 pr = *(const float4*)&sPR[wv][r][0];
            float hv = fmaf(pr.x, w0, fmaf(pr.y, w1, fmaf(pr.z, w2c, cc1)));
            hv = fmaxf(hv, 0.f);
            X[(r * 64 + lane) ^ ((r & 7) << 3)] = (__bf16)hv;   // swizzled bf16 store
        }
    }

    // ---------- Phase B: pos_em = h @ W2f + b2 (kept in registers)
    bf16x8 hf[2][2];
    #pragma unroll
    for (int rb = 0; rb < 2; ++rb)
        #pragma unroll
        for (int ks = 0; ks < 2; ++ks) {
            int row = rb * 16 + ln;
            hf[rb][ks] = *(const bf16x8*)&X[(row * 64 + ks * 32 + lg * 8) ^ ((row & 7) << 3)];
        }
    f32x4 pacc[2][4];
    #pragma unroll
    for (int rb = 0; rb < 2; ++rb)
        #pragma unroll
        for (int cb = 0; cb < 4; ++cb) pacc[rb][cb] = f32x4{0.f, 0.f, 0.f, 0.f};
    #pragma unroll
    for (int cb = 0; cb < 4; ++cb)
        #pragma unroll
        for (int ks = 0; ks < 2; ++ks) {
            bf16x8 wf = *(const bf16x8*)(w2f + (size_t)((cb * 2 + ks) * 64 + lane) * 8);
            pacc[0][cb] = MFMA16(hf[0][ks], wf, pacc[0][cb]);
            pacc[1][cb] = MFMA16(hf[1][ks], wf, pacc[1][cb]);
        }

    // pos_em regs + build X = qk_rel + pos_em  (accum layout: col=ln, row=lg*4+jj)
    float posem[2][4][4];
    #pragma unroll
    for (int rb = 0; rb < 2; ++rb) {
        const int nrow = n0 + rb;
        float qv[4];
        #pragma unroll
        for (int cb = 0; cb < 4; ++cb) {
            qv[cb] = query[(b * NN + nrow) * 64 + cb * 16 + ln];
            float c2v = b2[cb * 16 + ln];
            #pragma unroll
            for (int jj = 0; jj < 4; ++jj)
                posem[rb][cb][jj] = pacc[rb][cb][jj] + c2v;
        }
        #pragma unroll
        for (int jj = 0; jj < 4; ++jj) {
            int row = rb * 16 + lg * 4 + jj;
            int jb = (b * NN + sJ[wv][row]) * 64;
            #pragma unroll
            for (int cb = 0; cb < 4; ++cb) {
                float x = qv[cb] - key[jb + cb * 16 + ln] + posem[rb][cb][jj];
                X[(row * 64 + cb * 16 + ln) ^ ((row & 7) << 3)] = (__bf16)x;
            }
        }
    }

    // ---------- load X fragments, then stash posem into X's LDS space (X is dead after xf)
    bf16x8 xf[2][2];
    #pragma unroll
    for (int rb = 0; rb < 2; ++rb)
        #pragma unroll
        for (int ks = 0; ks < 2; ++ks) {
            int row = rb * 16 + ln;
            xf[rb][ks] = *(const bf16x8*)&X[(row * 64 + ks * 32 + lg * 8) ^ ((row & 7) << 3)];
        }
    // posem stash: linear [row][col] bf16; each lane writes (later re-reads) its own elems.
    // Frees ~32 VGPRs across the cc loop so the 128-reg cap holds without spills.
    #pragma unroll
    for (int rb = 0; rb < 2; ++rb)
        #pragma unroll
        for (int cb = 0; cb < 4; ++cb)
            #pragma unroll
            for (int jj = 0; jj < 4; ++jj) {
                int row = rb * 16 + lg * 4 + jj;
                X[row * 64 + cb * 16 + ln] = (__bf16)posem[rb][cb][jj];
            }

    // ---------- Phase D: A1 = relu(X @ W3f + c3f); a2 += A1 @ W4f   (4 col-chunks)
    f32x4 acc2[2][4];
    #pragma unroll
    for (int rb = 0; rb < 2; ++rb)
        #pragma unroll
        for (int nb = 0; nb < 4; ++nb) acc2[rb][nb] = f32x4{0.f, 0.f, 0.f, 0.f};

    for (int cc = 0; cc < 4; ++cc) {
        f32x4 g1a[2][4];
        #pragma unroll
        for (int rb = 0; rb < 2; ++rb)
            #pragma unroll
            for (int cb = 0; cb < 4; ++cb) g1a[rb][cb] = f32x4{0.f, 0.f, 0.f, 0.f};
        #pragma unroll
        for (int cb = 0; cb < 4; ++cb) {
            int nb = cc * 4 + cb;
            #pragma unroll
            for (int ks = 0; ks < 2; ++ks) {
                bf16x8 wf = *(const bf16x8*)(w3f + (size_t)((nb * 2 + ks) * 64 + lane) * 8);
                g1a[0][cb] = MFMA16(xf[0][ks], wf, g1a[0][cb]);
                g1a[1][cb] = MFMA16(xf[1][ks], wf, g1a[1][cb]);
            }
        }
        // epilogue: bias+relu -> bf16 -> swizzled LDS chunk (transpose bounce)
        #pragma unroll
        for (int cb = 0; cb < 4; ++cb) {
            float c3v = c3f[(cc * 4 + cb) * 16 + ln];
            #pragma unroll
            for (int rb = 0; rb < 2; ++rb)
                #pragma unroll
                for (int jj = 0; jj < 4; ++jj) {
                    int row = rb * 16 + lg * 4 + jj;
                    float v = fmaxf(g1a[rb][cb][jj] + c3v, 0.f);
                    A1[(row * 64 + cb * 16 + ln) ^ ((row & 7) << 3)] = (__bf16)v;
                }
        }
        // GEMM2 partial over this K-chunk (64 wide)
        #pragma unroll
        for (int kb2 = 0; kb2 < 2; ++kb2) {
            bf16x8 a1f[2];
            #pragma unroll
            for (int rb = 0; rb < 2; ++rb) {
                int row = rb * 16 + ln;
                a1f[rb] = *(const bf16x8*)&A1[(row * 64 + kb2 * 32 + lg * 8) ^ ((row & 7) << 3)];
            }
            #pragma unroll
            for (int nb = 0; nb < 4; ++nb) {
                bf16x8 wf = *(const bf16x8*)(w4f + (size_t)((nb * 8 + cc * 2 + kb2) * 64 + lane) * 8);
                acc2[0][nb] = MFMA16(a1f[0], wf, acc2[0][nb]);
                acc2[1][nb] = MFMA16(a1f[1], wf, acc2[1][nb]);
            }
        }
    }

    // ---------- Phase F: channel softmax + weighted sum over K neighbors
    #pragma unroll
    for (int rb = 0; rb < 2; ++rb) {
        const int nrow = n0 + rb;
        float val[4][4];
        #pragma unroll
        for (int nb = 0; nb < 4; ++nb) {
            float b4v = b4[nb * 16 + ln] * 0.125f;
            #pragma unroll
            for (int jj = 0; jj < 4; ++jj) val[nb][jj] = acc2[rb][nb][jj] + b4v;
        }
        float vv[4];
        #pragma unroll
        for (int nb = 0; nb < 4; ++nb) vv[nb] = value[(b * NN + nrow) * 64 + nb * 16 + ln];

        float res[4] = {0.f, 0.f, 0.f, 0.f};
        #pragma unroll
        for (int jj = 0; jj < 4; ++jj) {   // each jj = one neighbor row per lane group
            float m = fmaxf(fmaxf(val[0][jj], val[1][jj]), fmaxf(val[2][jj], val[3][jj]));
            #pragma unroll
            for (int d = 1; d < 16; d <<= 1) m = fmaxf(m, __shfl_xor(m, d, 64));
            float e0 = __expf(val[0][jj] - m), e1 = __expf(val[1][jj] - m);
            float e2 = __expf(val[2][jj] - m), e3 = __expf(val[3][jj] - m);
            float s = e0 + e1 + e2 + e3;
            #pragma unroll
            for (int d = 1; d < 16; d <<= 1) s += __shfl_xor(s, d, 64);
            float inv = 1.0f / s;
            int rowb = (rb * 16 + lg * 4) * 64 + ln;   // posem stash base for jj=0
            float p0 = (float)X[rowb + jj * 64 +  0];
            float p1 = (float)X[rowb + jj * 64 + 16];
            float p2 = (float)X[rowb + jj * 64 + 32];
            float p3 = (float)X[rowb + jj * 64 + 48];
            res[0] = fmaf(e0 * inv, vv[0] + p0, res[0]);
            res[1] = fmaf(e1 * inv, vv[1] + p1, res[1]);
            res[2] = fmaf(e2 * inv, vv[2] + p2, res[2]);
            res[3] = fmaf(e3 * inv, vv[3] + p3, res[3]);
        }
        #pragma unroll
        for (int nb = 0; nb < 4; ++nb) {   // sum over the 4 lane groups (16 neighbors total)
            res[nb] += __shfl_xor(res[nb], 16, 64);
            res[nb] += __shfl_xor(res[nb], 32, 64);
        }
        float o = (lg == 0) ? res[0] : (lg == 1) ? res[1] : (lg == 2) ? res[2] : res[3];
        out[(b * NN + nrow) * 64 + lane] = o;
    }
}

extern "C" void kernel_launch(void* const* d_in, const int* in_sizes, int n_in,
                              void* d_out, int out_size, void* d_ws, size_t ws_size,
                              hipStream_t stream) {
    const float* key   = (const float*)d_in[0];
    const float* query = (const float*)d_in[1];
    const float* value = (const float*)d_in[2];
    const float* pos   = (const float*)d_in[3];
    const int*   idx   = (const int*)d_in[4];
    const float* W1    = (const float*)d_in[5];
    const float* b1    = (const float*)d_in[6];
    const float* g1    = (const float*)d_in[7];
    const float* bt1   = (const float*)d_in[8];
    const float* W2    = (const float*)d_in[9];
    const float* b2    = (const float*)d_in[10];
    const float* W3    = (const float*)d_in[11];
    const float* b3    = (const float*)d_in[12];
    const float* g3    = (const float*)d_in[13];
    const float* bt3   = (const float*)d_in[14];
    const float* W4    = (const float*)d_in[15];
    const float* b4    = (const float*)d_in[16];
    unsigned char* ws  = (unsigned char*)d_ws;
    float* out = (float*)d_out;

    if (ws_size < WS_NEEDED) return;   // fail cleanly (absmax) instead of corrupting device memory

    hipLaunchKernelGGL(prep_kernel, dim3(146), dim3(256), 0, stream,
                       W1, b1, g1, bt1, W2, W3, b3, g3, bt3, W4, ws);
    hipLaunchKernelGGL(fused_kernel, dim3(8192), dim3(256), 0, stream,
                       key, query, value, pos, idx, b2, b4, ws, out);
}

// Round 5
// 396.650 us; speedup vs baseline: 1.0390x; 1.0390x over previous
//
#include <hip/hip_runtime.h>
#include <hip/hip_bf16.h>

typedef __bf16 bf16x8 __attribute__((ext_vector_type(8)));
typedef float  f32x4  __attribute__((ext_vector_type(4)));

#define MFMA16(A,B,C) __builtin_amdgcn_mfma_f32_16x16x32_bf16((A),(B),(C),0,0,0)

constexpr int NB = 8, NN = 8192, KK = 16;
constexpr size_t WS_NEEDED = 75776;

// ws layout (bytes):
//   w3f : [16 nb][2 ks][64 lane][8] bf16  -> 32768 B @ 0
//   w4f : [ 4 nb][8 kb][64 lane][8] bf16  -> 32768 B @ 32768
//   w2f : [ 4 nb][2 ks][64 lane][8] bf16  ->  8192 B @ 65536
//   W1f : [3][64] f32                     ->   768 B @ 73728
//   c1f : [64]  f32                       ->   256 B @ 74496
//   c3f : [256] f32                       ->  1024 B @ 74752

__global__ void prep_kernel(const float* __restrict__ W1, const float* __restrict__ b1,
                            const float* __restrict__ g1, const float* __restrict__ bt1,
                            const float* __restrict__ W2, const float* __restrict__ W3,
                            const float* __restrict__ b3, const float* __restrict__ g3,
                            const float* __restrict__ bt3, const float* __restrict__ W4,
                            unsigned char* __restrict__ ws)
{
    __bf16* w3f = (__bf16*)(ws);
    __bf16* w4f = (__bf16*)(ws + 32768);
    __bf16* w2f = (__bf16*)(ws + 65536);
    float*  W1f = (float*)(ws + 73728);
    float*  c1f = (float*)(ws + 74496);
    float*  c3f = (float*)(ws + 74752);

    const float inv = 1.0f / sqrtf(1.0f + 1e-3f);   // BN with init moving stats
    int t = blockIdx.x * 256 + threadIdx.x;

    if (t < 16384) {                    // W3 * s3 -> frag order
        int i = t & 7, lane = (t >> 3) & 63, r = t >> 9;
        int ks = r & 1, nb = r >> 1;
        int k = ks * 32 + (lane >> 4) * 8 + i;
        int n = nb * 16 + (lane & 15);
        w3f[t] = (__bf16)(W3[k * 256 + n] * (g3[n] * inv));
    } else if (t < 32768) {             // W4 / 8 -> frag order
        int u = t - 16384;
        int i = u & 7, lane = (u >> 3) & 63, r = u >> 9;
        int kb = r & 7, nb = r >> 3;
        int k = kb * 32 + (lane >> 4) * 8 + i;
        int n = nb * 16 + (lane & 15);
        w4f[u] = (__bf16)(W4[k * 64 + n] * 0.125f);
    } else if (t < 36864) {             // W2 -> frag order
        int u = t - 32768;
        int i = u & 7, lane = (u >> 3) & 63, r = u >> 9;
        int ks = r & 1, nb = r >> 1;
        int k = ks * 32 + (lane >> 4) * 8 + i;
        int n = nb * 16 + (lane & 15);
        w2f[u] = (__bf16)(W2[k * 64 + n]);
    } else if (t < 37056) {             // W1 * s1 (fp32)
        int u = t - 36864;              // u = d*64 + c
        int c = u & 63;
        W1f[u] = W1[u] * (g1[c] * inv);
    } else if (t < 37120) {             // c1f = b1*s1 + bt1
        int c = t - 37056;
        c1f[c] = b1[c] * (g1[c] * inv) + bt1[c];
    } else if (t < 37376) {             // c3f = b3*s3 + bt3
        int n = t - 37120;
        c3f[n] = b3[n] * (g3[n] * inv) + bt3[n];
    }
}

// One wave = 2 points (32 rows = 2x16 neighbor blocks). 4 waves/block, no barriers.
// __launch_bounds__(256,3): cap arch VGPR+AGPR at 170 -> 3 blocks/CU, no spills.
// History: (256,2) = 184 regs, 2 blocks/CU, 228 us. (256,4) cap 128 = massive scratch
// spills (WRITE_SIZE 16->221 MB), 333 us. Natural live set with posem stashed ~152.
__global__ __launch_bounds__(256, 3) void fused_kernel(
    const float* __restrict__ key, const float* __restrict__ query,
    const float* __restrict__ value, const float* __restrict__ pos,
    const int* __restrict__ idx, const float* __restrict__ b2,
    const float* __restrict__ b4, const unsigned char* __restrict__ ws,
    float* __restrict__ out)
{
    const __bf16* w3f = (const __bf16*)(ws);
    const __bf16* w4f = (const __bf16*)(ws + 32768);
    const __bf16* w2f = (const __bf16*)(ws + 65536);
    const float*  W1f = (const float*)(ws + 73728);
    const float*  c1f = (const float*)(ws + 74496);
    const float*  c3f = (const float*)(ws + 74752);

    __shared__ __attribute__((aligned(16))) __bf16 sX [4][2048];  // h, then X, then posem stash
    __shared__ __attribute__((aligned(16))) __bf16 sA1[4][2048];  // GEMM1 chunk bounce
    __shared__ __attribute__((aligned(16))) float  sPR[4][32][4]; // pos_rel per row
    __shared__ int sJ[4][32];                                      // neighbor idx per row

    const int wv   = threadIdx.x >> 6;
    const int lane = threadIdx.x & 63;
    const int lg   = lane >> 4;      // 16-lane group 0..3
    const int ln   = lane & 15;

    const int ptbase = blockIdx.x * 8 + wv * 2;  // global point of rb=0
    const int b  = ptbase >> 13;                 // / 8192
    const int n0 = ptbase & 8191;

    __bf16* X  = sX[wv];
    __bf16* A1 = sA1[wv];

    // ---------- Phase A: pos_rel, neighbor idx, h = relu(pos_rel @ W1f + c1f)
    if (lane < 32) {
        int p = lane >> 4, k = lane & 15;
        int n = n0 + p;
        int j = idx[(b * NN + n) * KK + k];
        sJ[wv][lane] = j;
        int pb = (b * NN + n) * 3, jb = (b * NN + j) * 3;
        sPR[wv][lane][0] = pos[pb + 0] - pos[jb + 0];
        sPR[wv][lane][1] = pos[pb + 1] - pos[jb + 1];
        sPR[wv][lane][2] = pos[pb + 2] - pos[jb + 2];
        sPR[wv][lane][3] = 0.f;
    }
    {
        // lane = output channel c
        float w0 = W1f[lane], w1 = W1f[64 + lane], w2c = W1f[128 + lane], cc1 = c1f[lane];
        for (int r = 0; r < 32; ++r) {
            float4 pr = *(const float4*)&sPR[wv][r][0];
            float hv = fmaf(pr.x, w0, fmaf(pr.y, w1, fmaf(pr.z, w2c, cc1)));
            hv = fmaxf(hv, 0.f);
            X[(r * 64 + lane) ^ ((r & 7) << 3)] = (__bf16)hv;   // swizzled bf16 store
        }
    }

    // ---------- Phase B: pos_em = h @ W2f + b2 (kept in registers)
    bf16x8 hf[2][2];
    #pragma unroll
    for (int rb = 0; rb < 2; ++rb)
        #pragma unroll
        for (int ks = 0; ks < 2; ++ks) {
            int row = rb * 16 + ln;
            hf[rb][ks] = *(const bf16x8*)&X[(row * 64 + ks * 32 + lg * 8) ^ ((row & 7) << 3)];
        }
    f32x4 pacc[2][4];
    #pragma unroll
    for (int rb = 0; rb < 2; ++rb)
        #pragma unroll
        for (int cb = 0; cb < 4; ++cb) pacc[rb][cb] = f32x4{0.f, 0.f, 0.f, 0.f};
    #pragma unroll
    for (int cb = 0; cb < 4; ++cb)
        #pragma unroll
        for (int ks = 0; ks < 2; ++ks) {
            bf16x8 wf = *(const bf16x8*)(w2f + (size_t)((cb * 2 + ks) * 64 + lane) * 8);
            pacc[0][cb] = MFMA16(hf[0][ks], wf, pacc[0][cb]);
            pacc[1][cb] = MFMA16(hf[1][ks], wf, pacc[1][cb]);
        }

    // pos_em regs + build X = qk_rel + pos_em  (accum layout: col=ln, row=lg*4+jj)
    float posem[2][4][4];
    #pragma unroll
    for (int rb = 0; rb < 2; ++rb) {
        const int nrow = n0 + rb;
        float qv[4];
        #pragma unroll
        for (int cb = 0; cb < 4; ++cb) {
            qv[cb] = query[(b * NN + nrow) * 64 + cb * 16 + ln];
            float c2v = b2[cb * 16 + ln];
            #pragma unroll
            for (int jj = 0; jj < 4; ++jj)
                posem[rb][cb][jj] = pacc[rb][cb][jj] + c2v;
        }
        #pragma unroll
        for (int jj = 0; jj < 4; ++jj) {
            int row = rb * 16 + lg * 4 + jj;
            int jb = (b * NN + sJ[wv][row]) * 64;
            #pragma unroll
            for (int cb = 0; cb < 4; ++cb) {
                float x = qv[cb] - key[jb + cb * 16 + ln] + posem[rb][cb][jj];
                X[(row * 64 + cb * 16 + ln) ^ ((row & 7) << 3)] = (__bf16)x;
            }
        }
    }

    // ---------- load X fragments, then stash posem into X's LDS space (X is dead after xf)
    bf16x8 xf[2][2];
    #pragma unroll
    for (int rb = 0; rb < 2; ++rb)
        #pragma unroll
        for (int ks = 0; ks < 2; ++ks) {
            int row = rb * 16 + ln;
            xf[rb][ks] = *(const bf16x8*)&X[(row * 64 + ks * 32 + lg * 8) ^ ((row & 7) << 3)];
        }
    // posem stash: lane-interleaved X[i*64 + lane], i = rb*16+cb*4+jj. Uniform i across
    // the wave per access -> bank = lane/2 mod 32 = 2-way = free (round-3 linear layout
    // was 8-way: 4.2M conflicts). Frees ~32 VGPRs across the cc loop.
    #pragma unroll
    for (int rb = 0; rb < 2; ++rb)
        #pragma unroll
        for (int cb = 0; cb < 4; ++cb)
            #pragma unroll
            for (int jj = 0; jj < 4; ++jj)
                X[(rb * 16 + cb * 4 + jj) * 64 + lane] = (__bf16)posem[rb][cb][jj];

    // ---------- Phase D: A1 = relu(X @ W3f + c3f); a2 += A1 @ W4f   (4 col-chunks)
    f32x4 acc2[2][4];
    #pragma unroll
    for (int rb = 0; rb < 2; ++rb)
        #pragma unroll
        for (int nb = 0; nb < 4; ++nb) acc2[rb][nb] = f32x4{0.f, 0.f, 0.f, 0.f};

    for (int cc = 0; cc < 4; ++cc) {
        f32x4 g1a[2][4];
        #pragma unroll
        for (int rb = 0; rb < 2; ++rb)
            #pragma unroll
            for (int cb = 0; cb < 4; ++cb) g1a[rb][cb] = f32x4{0.f, 0.f, 0.f, 0.f};
        #pragma unroll
        for (int cb = 0; cb < 4; ++cb) {
            int nb = cc * 4 + cb;
            #pragma unroll
            for (int ks = 0; ks < 2; ++ks) {
                bf16x8 wf = *(const bf16x8*)(w3f + (size_t)((nb * 2 + ks) * 64 + lane) * 8);
                g1a[0][cb] = MFMA16(xf[0][ks], wf, g1a[0][cb]);
                g1a[1][cb] = MFMA16(xf[1][ks], wf, g1a[1][cb]);
            }
        }
        // epilogue: bias+relu -> bf16 -> swizzled LDS chunk (transpose bounce)
        #pragma unroll
        for (int cb = 0; cb < 4; ++cb) {
            float c3v = c3f[(cc * 4 + cb) * 16 + ln];
            #pragma unroll
            for (int rb = 0; rb < 2; ++rb)
                #pragma unroll
                for (int jj = 0; jj < 4; ++jj) {
                    int row = rb * 16 + lg * 4 + jj;
                    float v = fmaxf(g1a[rb][cb][jj] + c3v, 0.f);
                    A1[(row * 64 + cb * 16 + ln) ^ ((row & 7) << 3)] = (__bf16)v;
                }
        }
        // GEMM2 partial over this K-chunk (64 wide)
        #pragma unroll
        for (int kb2 = 0; kb2 < 2; ++kb2) {
            bf16x8 a1f[2];
            #pragma unroll
            for (int rb = 0; rb < 2; ++rb) {
                int row = rb * 16 + ln;
                a1f[rb] = *(const bf16x8*)&A1[(row * 64 + kb2 * 32 + lg * 8) ^ ((row & 7) << 3)];
            }
            #pragma unroll
            for (int nb = 0; nb < 4; ++nb) {
                bf16x8 wf = *(const bf16x8*)(w4f + (size_t)((nb * 8 + cc * 2 + kb2) * 64 + lane) * 8);
                acc2[0][nb] = MFMA16(a1f[0], wf, acc2[0][nb]);
                acc2[1][nb] = MFMA16(a1f[1], wf, acc2[1][nb]);
            }
        }
    }

    // ---------- Phase F: channel softmax + weighted sum over K neighbors
    #pragma unroll
    for (int rb = 0; rb < 2; ++rb) {
        const int nrow = n0 + rb;
        float val[4][4];
        #pragma unroll
        for (int nb = 0; nb < 4; ++nb) {
            float b4v = b4[nb * 16 + ln] * 0.125f;
            #pragma unroll
            for (int jj = 0; jj < 4; ++jj) val[nb][jj] = acc2[rb][nb][jj] + b4v;
        }
        float vv[4];
        #pragma unroll
        for (int nb = 0; nb < 4; ++nb) vv[nb] = value[(b * NN + nrow) * 64 + nb * 16 + ln];

        float res[4] = {0.f, 0.f, 0.f, 0.f};
        #pragma unroll
        for (int jj = 0; jj < 4; ++jj) {   // each jj = one neighbor row per lane group
            float m = fmaxf(fmaxf(val[0][jj], val[1][jj]), fmaxf(val[2][jj], val[3][jj]));
            #pragma unroll
            for (int d = 1; d < 16; d <<= 1) m = fmaxf(m, __shfl_xor(m, d, 64));
            float e0 = __expf(val[0][jj] - m), e1 = __expf(val[1][jj] - m);
            float e2 = __expf(val[2][jj] - m), e3 = __expf(val[3][jj] - m);
            float s = e0 + e1 + e2 + e3;
            #pragma unroll
            for (int d = 1; d < 16; d <<= 1) s += __shfl_xor(s, d, 64);
            float inv = 1.0f / s;
            float p0 = (float)X[(rb * 16 +  0 + jj) * 64 + lane];
            float p1 = (float)X[(rb * 16 +  4 + jj) * 64 + lane];
            float p2 = (float)X[(rb * 16 +  8 + jj) * 64 + lane];
            float p3 = (float)X[(rb * 16 + 12 + jj) * 64 + lane];
            res[0] = fmaf(e0 * inv, vv[0] + p0, res[0]);
            res[1] = fmaf(e1 * inv, vv[1] + p1, res[1]);
            res[2] = fmaf(e2 * inv, vv[2] + p2, res[2]);
            res[3] = fmaf(e3 * inv, vv[3] + p3, res[3]);
        }
        #pragma unroll
        for (int nb = 0; nb < 4; ++nb) {   // sum over the 4 lane groups (16 neighbors total)
            res[nb] += __shfl_xor(res[nb], 16, 64);
            res[nb] += __shfl_xor(res[nb], 32, 64);
        }
        float o = (lg == 0) ? res[0] : (lg == 1) ? res[1] : (lg == 2) ? res[2] : res[3];
        out[(b * NN + nrow) * 64 + lane] = o;
    }
}

extern "C" void kernel_launch(void* const* d_in, const int* in_sizes, int n_in,
                              void* d_out, int out_size, void* d_ws, size_t ws_size,
                              hipStream_t stream) {
    const float* key   = (const float*)d_in[0];
    const float* query = (const float*)d_in[1];
    const float* value = (const float*)d_in[2];
    const float* pos   = (const float*)d_in[3];
    const int*   idx   = (const int*)d_in[4];
    const float* W1    = (const float*)d_in[5];
    const float* b1    = (const float*)d_in[6];
    const float* g1    = (const float*)d_in[7];
    const float* bt1   = (const float*)d_in[8];
    const float* W2    = (const float*)d_in[9];
    const float* b2    = (const float*)d_in[10];
    const float* W3    = (const float*)d_in[11];
    const float* b3    = (const float*)d_in[12];
    const float* g3    = (const float*)d_in[13];
    const float* bt3   = (const float*)d_in[14];
    const float* W4    = (const float*)d_in[15];
    const float* b4    = (const float*)d_in[16];
    unsigned char* ws  = (unsigned char*)d_ws;
    float* out = (float*)d_out;

    if (ws_size < WS_NEEDED) return;   // fail cleanly (absmax) instead of corrupting device memory

    hipLaunchKernelGGL(prep_kernel, dim3(146), dim3(256), 0, stream,
                       W1, b1, g1, bt1, W2, W3, b3, g3, bt3, W4, ws);
    hipLaunchKernelGGL(fused_kernel, dim3(8192), dim3(256), 0, stream,
                       key, query, value, pos, idx, b2, b4, ws, out);
}

// Round 9
// 261.980 us; speedup vs baseline: 1.5732x; 1.5140x over previous
//
#include <hip/hip_runtime.h>
#include <hip/hip_bf16.h>

typedef __bf16 bf16x8 __attribute__((ext_vector_type(8)));
typedef __bf16 bf16x4 __attribute__((ext_vector_type(4)));
typedef float  f32x4  __attribute__((ext_vector_type(4)));

#define MFMA16(A,B,C) __builtin_amdgcn_mfma_f32_16x16x32_bf16((A),(B),(C),0,0,0)

constexpr int NB = 8, NN = 8192, KK = 16;
constexpr int XS = 72;            // LDS row stride (elements): 144B = 16B-aligned, not 0 mod 128B
constexpr size_t WS_NEEDED = 78848;

// All GEMM contractions use a PERMUTED k-order (exact: A-storage and B-frag permute identically).
// Channel c = cb*16 + u  <->  slot p = u*4 + cb   (c64(p) = (p&3)*16 + (p>>2))
// This makes each lane's 4 C-layout epilogue values contiguous -> one ds_write_b64.
//
// ws layout (bytes):
//   w3f : [16 nb][2 ks][64 lane][8] bf16  -> 32768 @ 0      (k-slot p=ks*32+kk -> W3 row c64(p), *s3)
//   w4f : [ 4 nb][8 kb][64 lane][8] bf16  -> 32768 @ 32768  (kb=cc*2+kb2; c = cc*64 + c64((kb&1)*32+kk), /8)
//   w2f : [ 4 nb][2 ks][64 lane][8] bf16  ->  8192 @ 65536  (k-slot -> W2 row c64(p))
//   w1f : [ 4 nb][64 lane][8]      bf16  ->  4096 @ 73728  (k=0..2: W1*s1; k=3: c1 bias row; k>3: 0)
//   c3f : [256] f32                      ->  1024 @ 77824

__global__ void prep_kernel(const float* __restrict__ W1, const float* __restrict__ b1,
                            const float* __restrict__ g1, const float* __restrict__ bt1,
                            const float* __restrict__ W2, const float* __restrict__ W3,
                            const float* __restrict__ b3, const float* __restrict__ g3,
                            const float* __restrict__ bt3, const float* __restrict__ W4,
                            unsigned char* __restrict__ ws)
{
    __bf16* w3f = (__bf16*)(ws);
    __bf16* w4f = (__bf16*)(ws + 32768);
    __bf16* w2f = (__bf16*)(ws + 65536);
    __bf16* w1f = (__bf16*)(ws + 73728);
    float*  c3f = (float*)(ws + 77824);

    const float inv = 1.0f / sqrtf(1.0f + 1e-3f);   // BN with init moving stats
    int t = blockIdx.x * 256 + threadIdx.x;

    if (t < 16384) {                    // w3f
        int i = t & 7, lane = (t >> 3) & 63, r = t >> 9;
        int ks = r & 1, nb = r >> 1;
        int p = ks * 32 + (lane >> 4) * 8 + i;
        int c = (p & 3) * 16 + (p >> 2);
        int n = nb * 16 + (lane & 15);
        w3f[t] = (__bf16)(W3[c * 256 + n] * (g3[n] * inv));
    } else if (t < 32768) {             // w4f
        int u = t - 16384;
        int i = u & 7, lane = (u >> 3) & 63, r = u >> 9;
        int kb = r & 7, nb = r >> 3;
        int q = (kb & 1) * 32 + (lane >> 4) * 8 + i;
        int c = (kb >> 1) * 64 + (q & 3) * 16 + (q >> 2);
        int n = nb * 16 + (lane & 15);
        w4f[u] = (__bf16)(W4[c * 64 + n] * 0.125f);
    } else if (t < 36864) {             // w2f
        int u = t - 32768;
        int i = u & 7, lane = (u >> 3) & 63, r = u >> 9;
        int ks = r & 1, nb = r >> 1;
        int p = ks * 32 + (lane >> 4) * 8 + i;
        int c = (p & 3) * 16 + (p >> 2);
        int n = nb * 16 + (lane & 15);
        w2f[u] = (__bf16)(W2[c * 64 + n]);
    } else if (t < 38912) {             // w1f (k=3 carries the BN-folded bias; A-side puts 1.0 there)
        int u = t - 36864;
        int i = u & 7, lane = (u >> 3) & 63, nb = u >> 9;
        int kk = (lane >> 4) * 8 + i;
        int n = nb * 16 + (lane & 15);
        float v = 0.f;
        if (kk < 3)       v = W1[kk * 64 + n] * (g1[n] * inv);
        else if (kk == 3) v = b1[n] * (g1[n] * inv) + bt1[n];
        w1f[u] = (__bf16)v;
    } else if (t < 39168) {             // c3f
        int n = t - 38912;
        c3f[n] = b3[n] * (g3[n] * inv) + bt3[n];
    }
}

// One wave = 2 points (32 rows = 2x16 neighbor blocks). 4 waves/block, no barriers.
// (256,2): r2=228us baseline config. r5 showed tighter reg caps destroy ILP (325us).
__global__ __launch_bounds__(256, 2) void fused_kernel(
    const float* __restrict__ key, const float* __restrict__ query,
    const float* __restrict__ value, const float* __restrict__ pos,
    const int* __restrict__ idx, const float* __restrict__ b2,
    const float* __restrict__ b4, const unsigned char* __restrict__ ws,
    float* __restrict__ out)
{
    const __bf16* w3f = (const __bf16*)(ws);
    const __bf16* w4f = (const __bf16*)(ws + 32768);
    const __bf16* w2f = (const __bf16*)(ws + 65536);
    const __bf16* w1f = (const __bf16*)(ws + 73728);
    const float*  c3f = (const float*)(ws + 77824);

    const f32x4 ZERO4 = {0.f, 0.f, 0.f, 0.f};

    __shared__ __attribute__((aligned(16))) __bf16 sX [4][32 * XS];  // h, then X (permuted slots)
    __shared__ __attribute__((aligned(16))) __bf16 sA1[4][32 * XS];  // GEMM1 chunk bounce
    __shared__ __attribute__((aligned(16))) float  sPR[4][32][4];    // pos_rel per row
    __shared__ int sJ[4][32];                                        // neighbor idx per row

    const int wv   = threadIdx.x >> 6;
    const int lane = threadIdx.x & 63;
    const int lg   = lane >> 4;      // 16-lane group 0..3
    const int ln   = lane & 15;

    const int ptbase = blockIdx.x * 8 + wv * 2;  // global point of rb=0
    const int b  = ptbase >> 13;                 // / 8192
    const int n0 = ptbase & 8191;

    __bf16* X  = sX[wv];
    __bf16* A1 = sA1[wv];

    // ---------- Phase A: pos_rel + h = relu(PR @ W1f) via MFMA (bias folded at k=3)
    if (lane < 32) {
        int p = lane >> 4, k = lane & 15;
        int n = n0 + p;
        int j = idx[(b * NN + n) * KK + k];
        sJ[wv][lane] = j;
        int pb = (b * NN + n) * 3, jb = (b * NN + j) * 3;
        sPR[wv][lane][0] = pos[pb + 0] - pos[jb + 0];
        sPR[wv][lane][1] = pos[pb + 1] - pos[jb + 1];
        sPR[wv][lane][2] = pos[pb + 2] - pos[jb + 2];
        sPR[wv][lane][3] = 0.f;
    }
    bf16x8 af[2];
    #pragma unroll
    for (int rb = 0; rb < 2; ++rb) {
        bf16x8 a;
        #pragma unroll
        for (int i = 0; i < 8; ++i) a[i] = (__bf16)0.0f;
        if (lg == 0) {
            const float4 pr = *(const float4*)&sPR[wv][rb * 16 + ln][0];
            a[0] = (__bf16)pr.x; a[1] = (__bf16)pr.y; a[2] = (__bf16)pr.z;
            a[3] = (__bf16)1.0f;
        }
        af[rb] = a;
    }
    f32x4 pa[2][4];
    #pragma unroll
    for (int nb = 0; nb < 4; ++nb) {
        bf16x8 wf = *(const bf16x8*)(w1f + (size_t)(nb * 64 + lane) * 8);
        pa[0][nb] = MFMA16(af[0], wf, ZERO4);
        pa[1][nb] = MFMA16(af[1], wf, ZERO4);
    }
    // h epilogue: relu -> packed b64 at permuted slots (slot p = ln*4 + nb)
    #pragma unroll
    for (int rb = 0; rb < 2; ++rb)
        #pragma unroll
        for (int jj = 0; jj < 4; ++jj) {
            int row = rb * 16 + lg * 4 + jj;
            bf16x4 hv;
            #pragma unroll
            for (int nb = 0; nb < 4; ++nb) hv[nb] = (__bf16)fmaxf(pa[rb][nb][jj], 0.f);
            *(bf16x4*)&X[row * XS + ln * 4] = hv;
        }

    // ---------- Phase B: pos_em = h @ W2f + b2 (kept in registers)
    bf16x8 hf[2][2];
    #pragma unroll
    for (int rb = 0; rb < 2; ++rb)
        #pragma unroll
        for (int ks = 0; ks < 2; ++ks)
            hf[rb][ks] = *(const bf16x8*)&X[(rb * 16 + ln) * XS + ks * 32 + lg * 8];
    f32x4 pacc[2][4];
    #pragma unroll
    for (int rb = 0; rb < 2; ++rb)
        #pragma unroll
        for (int cb = 0; cb < 4; ++cb) pacc[rb][cb] = ZERO4;
    #pragma unroll
    for (int cb = 0; cb < 4; ++cb)
        #pragma unroll
        for (int ks = 0; ks < 2; ++ks) {
            bf16x8 wf = *(const bf16x8*)(w2f + (size_t)((cb * 2 + ks) * 64 + lane) * 8);
            pacc[0][cb] = MFMA16(hf[0][ks], wf, pacc[0][cb]);
            pacc[1][cb] = MFMA16(hf[1][ks], wf, pacc[1][cb]);
        }

    // posem regs (C-layout: col=ln, row=lg*4+jj) + X = qk_rel + pos_em, packed write
    float posem[2][4][4];
    #pragma unroll
    for (int rb = 0; rb < 2; ++rb) {
        const int nrow = n0 + rb;
        float qv[4];
        #pragma unroll
        for (int cb = 0; cb < 4; ++cb) {
            qv[cb] = query[(b * NN + nrow) * 64 + cb * 16 + ln];
            float c2v = b2[cb * 16 + ln];
            #pragma unroll
            for (int jj = 0; jj < 4; ++jj)
                posem[rb][cb][jj] = pacc[rb][cb][jj] + c2v;
        }
        #pragma unroll
        for (int jj = 0; jj < 4; ++jj) {
            int row = rb * 16 + lg * 4 + jj;
            int jb = (b * NN + sJ[wv][row]) * 64;
            bf16x4 xv;
            #pragma unroll
            for (int cb = 0; cb < 4; ++cb)
                xv[cb] = (__bf16)(qv[cb] - key[jb + cb * 16 + ln] + posem[rb][cb][jj]);
            *(bf16x4*)&X[row * XS + ln * 4] = xv;
        }
    }

    // ---------- Phase D: A1 = relu(X @ W3f + c3f); acc2 += A1 @ W4f  (4 col-chunks of 64)
    bf16x8 xf[2][2];
    #pragma unroll
    for (int rb = 0; rb < 2; ++rb)
        #pragma unroll
        for (int ks = 0; ks < 2; ++ks)
            xf[rb][ks] = *(const bf16x8*)&X[(rb * 16 + ln) * XS + ks * 32 + lg * 8];
    f32x4 acc2[2][4];
    #pragma unroll
    for (int rb = 0; rb < 2; ++rb)
        #pragma unroll
        for (int nb = 0; nb < 4; ++nb) acc2[rb][nb] = ZERO4;

    for (int cc = 0; cc < 4; ++cc) {
        f32x4 g1a[2][4];
        #pragma unroll
        for (int rb = 0; rb < 2; ++rb)
            #pragma unroll
            for (int cb = 0; cb < 4; ++cb) g1a[rb][cb] = ZERO4;
        #pragma unroll
        for (int cb = 0; cb < 4; ++cb) {
            int nb = cc * 4 + cb;
            #pragma unroll
            for (int ks = 0; ks < 2; ++ks) {
                bf16x8 wf = *(const bf16x8*)(w3f + (size_t)((nb * 2 + ks) * 64 + lane) * 8);
                g1a[0][cb] = MFMA16(xf[0][ks], wf, g1a[0][cb]);
                g1a[1][cb] = MFMA16(xf[1][ks], wf, g1a[1][cb]);
            }
        }
        // epilogue: bias+relu -> packed b64 at permuted slots (chunk-local p = ln*4 + cb)
        float c3v[4];
        #pragma unroll
        for (int cb = 0; cb < 4; ++cb) c3v[cb] = c3f[(cc * 4 + cb) * 16 + ln];
        #pragma unroll
        for (int rb = 0; rb < 2; ++rb)
            #pragma unroll
            for (int jj = 0; jj < 4; ++jj) {
                int row = rb * 16 + lg * 4 + jj;
                bf16x4 av;
                #pragma unroll
                for (int cb = 0; cb < 4; ++cb)
                    av[cb] = (__bf16)fmaxf(g1a[rb][cb][jj] + c3v[cb], 0.f);
                *(bf16x4*)&A1[row * XS + ln * 4] = av;
            }
        // GEMM2 partial over this 64-wide chunk
        #pragma unroll
        for (int kb2 = 0; kb2 < 2; ++kb2) {
            bf16x8 a1f[2];
            #pragma unroll
            for (int rb = 0; rb < 2; ++rb)
                a1f[rb] = *(const bf16x8*)&A1[(rb * 16 + ln) * XS + kb2 * 32 + lg * 8];
            #pragma unroll
            for (int nb = 0; nb < 4; ++nb) {
                bf16x8 wf = *(const bf16x8*)(w4f + (size_t)((nb * 8 + cc * 2 + kb2) * 64 + lane) * 8);
                acc2[0][nb] = MFMA16(a1f[0], wf, acc2[0][nb]);
                acc2[1][nb] = MFMA16(a1f[1], wf, acc2[1][nb]);
            }
        }
    }

    // ---------- Phase F: channel softmax (no max-sub: logits O(1), f32-exp safe, exact ratios)
    float b4v[4];
    #pragma unroll
    for (int nb = 0; nb < 4; ++nb) b4v[nb] = b4[nb * 16 + ln] * 0.125f;
    #pragma unroll
    for (int rb = 0; rb < 2; ++rb) {
        const int nrow = n0 + rb;
        float vv[4];
        #pragma unroll
        for (int nb = 0; nb < 4; ++nb) vv[nb] = value[(b * NN + nrow) * 64 + nb * 16 + ln];

        float res[4] = {0.f, 0.f, 0.f, 0.f};
        #pragma unroll
        for (int jj = 0; jj < 4; ++jj) {   // each jj = one neighbor row per lane group
            float e0 = __expf(acc2[rb][0][jj] + b4v[0]);
            float e1 = __expf(acc2[rb][1][jj] + b4v[1]);
            float e2 = __expf(acc2[rb][2][jj] + b4v[2]);
            float e3 = __expf(acc2[rb][3][jj] + b4v[3]);
            float s = (e0 + e1) + (e2 + e3);
            #pragma unroll
            for (int d = 1; d < 16; d <<= 1) s += __shfl_xor(s, d, 64);
            float inv = 1.0f / s;
            res[0] = fmaf(e0 * inv, vv[0] + posem[rb][0][jj], res[0]);
            res[1] = fmaf(e1 * inv, vv[1] + posem[rb][1][jj], res[1]);
            res[2] = fmaf(e2 * inv, vv[2] + posem[rb][2][jj], res[2]);
            res[3] = fmaf(e3 * inv, vv[3] + posem[rb][3][jj], res[3]);
        }
        #pragma unroll
        for (int nb = 0; nb < 4; ++nb) {   // sum over the 4 lane groups (16 neighbors total)
            res[nb] += __shfl_xor(res[nb], 16, 64);
            res[nb] += __shfl_xor(res[nb], 32, 64);
        }
        float o = (lg == 0) ? res[0] : (lg == 1) ? res[1] : (lg == 2) ? res[2] : res[3];
        out[(b * NN + nrow) * 64 + lane] = o;
    }
}

extern "C" void kernel_launch(void* const* d_in, const int* in_sizes, int n_in,
                              void* d_out, int out_size, void* d_ws, size_t ws_size,
                              hipStream_t stream) {
    const float* key   = (const float*)d_in[0];
    const float* query = (const float*)d_in[1];
    const float* value = (const float*)d_in[2];
    const float* pos   = (const float*)d_in[3];
    const int*   idx   = (const int*)d_in[4];
    const float* W1    = (const float*)d_in[5];
    const float* b1    = (const float*)d_in[6];
    const float* g1    = (const float*)d_in[7];
    const float* bt1   = (const float*)d_in[8];
    const float* W2    = (const float*)d_in[9];
    const float* b2    = (const float*)d_in[10];
    const float* W3    = (const float*)d_in[11];
    const float* b3    = (const float*)d_in[12];
    const float* g3    = (const float*)d_in[13];
    const float* bt3   = (const float*)d_in[14];
    const float* W4    = (const float*)d_in[15];
    const float* b4    = (const float*)d_in[16];
    unsigned char* ws  = (unsigned char*)d_ws;
    float* out = (float*)d_out;

    if (ws_size < WS_NEEDED) return;   // fail cleanly instead of corrupting device memory

    hipLaunchKernelGGL(prep_kernel, dim3(153), dim3(256), 0, stream,
                       W1, b1, g1, bt1, W2, W3, b3, g3, bt3, W4, ws);
    hipLaunchKernelGGL(fused_kernel, dim3(8192), dim3(256), 0, stream,
                       key, query, value, pos, idx, b2, b4, ws, out);
}

// Round 10
// 257.195 us; speedup vs baseline: 1.6024x; 1.0186x over previous
//
#include <hip/hip_runtime.h>
#include <hip/hip_bf16.h>

typedef __bf16 bf16x8 __attribute__((ext_vector_type(8)));
typedef __bf16 bf16x4 __attribute__((ext_vector_type(4)));
typedef float  f32x4  __attribute__((ext_vector_type(4)));

#define MFMA16(A,B,C) __builtin_amdgcn_mfma_f32_16x16x32_bf16((A),(B),(C),0,0,0)

constexpr int NB = 8, NN = 8192, KK = 16;
constexpr int XS = 72;            // LDS row stride (elements): 144B; conflicts measured negligible (1.3us)
constexpr size_t WS_NEEDED = 78848;

// Permuted k-order everywhere (exact): channel c = cb*16+u <-> slot p = u*4+cb.
// ws layout: w3f 32768 @0 | w4f 32768 @32768 | w2f 8192 @65536 | w1f 4096 @73728 | c3f 1024 @77824

__global__ void prep_kernel(const float* __restrict__ W1, const float* __restrict__ b1,
                            const float* __restrict__ g1, const float* __restrict__ bt1,
                            const float* __restrict__ W2, const float* __restrict__ W3,
                            const float* __restrict__ b3, const float* __restrict__ g3,
                            const float* __restrict__ bt3, const float* __restrict__ W4,
                            unsigned char* __restrict__ ws)
{
    __bf16* w3f = (__bf16*)(ws);
    __bf16* w4f = (__bf16*)(ws + 32768);
    __bf16* w2f = (__bf16*)(ws + 65536);
    __bf16* w1f = (__bf16*)(ws + 73728);
    float*  c3f = (float*)(ws + 77824);

    const float inv = 1.0f / sqrtf(1.0f + 1e-3f);   // BN with init moving stats
    int t = blockIdx.x * 256 + threadIdx.x;

    if (t < 16384) {                    // w3f
        int i = t & 7, lane = (t >> 3) & 63, r = t >> 9;
        int ks = r & 1, nb = r >> 1;
        int p = ks * 32 + (lane >> 4) * 8 + i;
        int c = (p & 3) * 16 + (p >> 2);
        int n = nb * 16 + (lane & 15);
        w3f[t] = (__bf16)(W3[c * 256 + n] * (g3[n] * inv));
    } else if (t < 32768) {             // w4f
        int u = t - 16384;
        int i = u & 7, lane = (u >> 3) & 63, r = u >> 9;
        int kb = r & 7, nb = r >> 3;
        int q = (kb & 1) * 32 + (lane >> 4) * 8 + i;
        int c = (kb >> 1) * 64 + (q & 3) * 16 + (q >> 2);
        int n = nb * 16 + (lane & 15);
        w4f[u] = (__bf16)(W4[c * 64 + n] * 0.125f);
    } else if (t < 36864) {             // w2f
        int u = t - 32768;
        int i = u & 7, lane = (u >> 3) & 63, r = u >> 9;
        int ks = r & 1, nb = r >> 1;
        int p = ks * 32 + (lane >> 4) * 8 + i;
        int c = (p & 3) * 16 + (p >> 2);
        int n = nb * 16 + (lane & 15);
        w2f[u] = (__bf16)(W2[c * 64 + n]);
    } else if (t < 38912) {             // w1f (k=3 = BN-folded bias row; A-side supplies 1.0)
        int u = t - 36864;
        int i = u & 7, lane = (u >> 3) & 63, nb = u >> 9;
        int kk = (lane >> 4) * 8 + i;
        int n = nb * 16 + (lane & 15);
        float v = 0.f;
        if (kk < 3)       v = W1[kk * 64 + n] * (g1[n] * inv);
        else if (kk == 3) v = b1[n] * (g1[n] * inv) + bt1[n];
        w1f[u] = (__bf16)v;
    } else if (t < 39168) {             // c3f
        int n = t - 38912;
        c3f[n] = b3[n] * (g3[n] * inv) + bt3[n];
    }
}

// One wave = 2 points. No barriers, no sJ/sPR LDS (shfl instead). All gathers prefetched
// ahead of the MFMA chain. Biases folded into MFMA C-in (b2->pacc, c3->g1a, b4->acc2).
__global__ __launch_bounds__(256, 2) void fused_kernel(
    const float* __restrict__ key, const float* __restrict__ query,
    const float* __restrict__ value, const float* __restrict__ pos,
    const int* __restrict__ idx, const float* __restrict__ b2,
    const float* __restrict__ b4, const unsigned char* __restrict__ ws,
    float* __restrict__ out)
{
    const __bf16* w3f = (const __bf16*)(ws);
    const __bf16* w4f = (const __bf16*)(ws + 32768);
    const __bf16* w2f = (const __bf16*)(ws + 65536);
    const __bf16* w1f = (const __bf16*)(ws + 73728);
    const float*  c3f = (const float*)(ws + 77824);

    const f32x4 ZERO4 = {0.f, 0.f, 0.f, 0.f};

    __shared__ __attribute__((aligned(16))) __bf16 sX [4][32 * XS];  // h, then X (permuted slots)
    __shared__ __attribute__((aligned(16))) __bf16 sA1[4][32 * XS];  // GEMM1 chunk bounce

    const int wv   = threadIdx.x >> 6;
    const int lane = threadIdx.x & 63;
    const int lg   = lane >> 4;      // 16-lane group 0..3
    const int ln   = lane & 15;

    const int ptbase = blockIdx.x * 8 + wv * 2;  // global point of rb=0
    const int b  = ptbase >> 13;                 // / 8192
    const int n0 = ptbase & 8191;

    __bf16* X  = sX[wv];
    __bf16* A1 = sA1[wv];

    // ---------- Prefetch wave-local inputs (issue ASAP; consumed much later)
    float qv[2][4], vvv[2][4], b4v[4];
    #pragma unroll
    for (int rb = 0; rb < 2; ++rb)
        #pragma unroll
        for (int cb = 0; cb < 4; ++cb) {
            qv[rb][cb]  = query[(b * NN + n0 + rb) * 64 + cb * 16 + ln];
            vvv[rb][cb] = value[(b * NN + n0 + rb) * 64 + cb * 16 + ln];
        }
    #pragma unroll
    for (int nb = 0; nb < 4; ++nb) b4v[nb] = b4[nb * 16 + ln] * 0.125f;
    float b2v[4];
    #pragma unroll
    for (int cb = 0; cb < 4; ++cb) b2v[cb] = b2[cb * 16 + ln];

    // idx + pos gather (lane<32 covers the 32 rows; row r of point p held by lane p*16+(r&15))
    int   jl = 0;
    float prx = 0.f, pry = 0.f, prz = 0.f;
    if (lane < 32) {
        int p = lane >> 4, k = lane & 15;
        int n = n0 + p;
        jl = idx[(b * NN + n) * KK + k];
        int pb = (b * NN + n) * 3, jb = (b * NN + jl) * 3;
        prx = pos[pb + 0] - pos[jb + 0];
        pry = pos[pb + 1] - pos[jb + 1];
        prz = pos[pb + 2] - pos[jb + 2];
    }

    // key gather prefetch: j via shfl (src lane rb*16+lg*4+jj), issue all 32 loads now --
    // their ~200cy L2 latency hides under Phase A+B MFMAs.
    float kreg[2][4][4];
    #pragma unroll
    for (int rb = 0; rb < 2; ++rb)
        #pragma unroll
        for (int jj = 0; jj < 4; ++jj) {
            int j = __shfl(jl, rb * 16 + lg * 4 + jj, 64);
            int jb = (b * NN + j) * 64;
            #pragma unroll
            for (int cb = 0; cb < 4; ++cb)
                kreg[rb][jj][cb] = key[jb + cb * 16 + ln];
        }

    // ---------- Phase A: h = relu(PR @ W1f) via MFMA (bias at k=3, A supplies 1.0)
    bf16x8 af[2];
    #pragma unroll
    for (int rb = 0; rb < 2; ++rb) {
        float ax = __shfl(prx, rb * 16 + ln, 64);
        float ay = __shfl(pry, rb * 16 + ln, 64);
        float az = __shfl(prz, rb * 16 + ln, 64);
        bf16x8 a;
        #pragma unroll
        for (int i = 0; i < 8; ++i) a[i] = (__bf16)0.0f;
        if (lg == 0) {
            a[0] = (__bf16)ax; a[1] = (__bf16)ay; a[2] = (__bf16)az;
            a[3] = (__bf16)1.0f;
        }
        af[rb] = a;
    }
    f32x4 pa[2][4];
    #pragma unroll
    for (int nb = 0; nb < 4; ++nb) {
        bf16x8 wf = *(const bf16x8*)(w1f + (size_t)(nb * 64 + lane) * 8);
        pa[0][nb] = MFMA16(af[0], wf, ZERO4);
        pa[1][nb] = MFMA16(af[1], wf, ZERO4);
    }
    // h epilogue: relu -> packed b64 at permuted slots (slot p = ln*4 + nb)
    #pragma unroll
    for (int rb = 0; rb < 2; ++rb)
        #pragma unroll
        for (int jj = 0; jj < 4; ++jj) {
            int row = rb * 16 + lg * 4 + jj;
            bf16x4 hv;
            #pragma unroll
            for (int nb = 0; nb < 4; ++nb) hv[nb] = (__bf16)fmaxf(pa[rb][nb][jj], 0.f);
            *(bf16x4*)&X[row * XS + ln * 4] = hv;
        }

    // ---------- Phase B: posem = h @ W2f + b2 (b2 folded into C-in; pacc IS posem)
    bf16x8 hf[2][2];
    #pragma unroll
    for (int rb = 0; rb < 2; ++rb)
        #pragma unroll
        for (int ks = 0; ks < 2; ++ks)
            hf[rb][ks] = *(const bf16x8*)&X[(rb * 16 + ln) * XS + ks * 32 + lg * 8];
    f32x4 pacc[2][4];
    #pragma unroll
    for (int rb = 0; rb < 2; ++rb)
        #pragma unroll
        for (int cb = 0; cb < 4; ++cb) {
            f32x4 c0 = {b2v[cb], b2v[cb], b2v[cb], b2v[cb]};
            pacc[rb][cb] = c0;
        }
    #pragma unroll
    for (int cb = 0; cb < 4; ++cb)
        #pragma unroll
        for (int ks = 0; ks < 2; ++ks) {
            bf16x8 wf = *(const bf16x8*)(w2f + (size_t)((cb * 2 + ks) * 64 + lane) * 8);
            pacc[0][cb] = MFMA16(hf[0][ks], wf, pacc[0][cb]);
            pacc[1][cb] = MFMA16(hf[1][ks], wf, pacc[1][cb]);
        }

    // X = qk_rel + posem, packed write (C-layout: col=ln, row=lg*4+jj)
    #pragma unroll
    for (int rb = 0; rb < 2; ++rb)
        #pragma unroll
        for (int jj = 0; jj < 4; ++jj) {
            int row = rb * 16 + lg * 4 + jj;
            bf16x4 xv;
            #pragma unroll
            for (int cb = 0; cb < 4; ++cb)
                xv[cb] = (__bf16)(qv[rb][cb] - kreg[rb][jj][cb] + pacc[rb][cb][jj]);
            *(bf16x4*)&X[row * XS + ln * 4] = xv;
        }

    // ---------- Phase D: A1 = relu(X @ W3f + c3); acc2 += A1 @ W4f  (4 col-chunks of 64)
    bf16x8 xf[2][2];
    #pragma unroll
    for (int rb = 0; rb < 2; ++rb)
        #pragma unroll
        for (int ks = 0; ks < 2; ++ks)
            xf[rb][ks] = *(const bf16x8*)&X[(rb * 16 + ln) * XS + ks * 32 + lg * 8];
    f32x4 acc2[2][4];
    #pragma unroll
    for (int rb = 0; rb < 2; ++rb)
        #pragma unroll
        for (int nb = 0; nb < 4; ++nb) {
            f32x4 c0 = {b4v[nb], b4v[nb], b4v[nb], b4v[nb]};
            acc2[rb][nb] = c0;   // b4 folded into GEMM2 C-in
        }

    for (int cc = 0; cc < 4; ++cc) {
        f32x4 g1a[2][4];
        #pragma unroll
        for (int cb = 0; cb < 4; ++cb) {
            float c3v = c3f[(cc * 4 + cb) * 16 + ln];
            f32x4 c0 = {c3v, c3v, c3v, c3v};
            g1a[0][cb] = c0;     // c3 folded into GEMM1 C-in
            g1a[1][cb] = c0;
        }
        #pragma unroll
        for (int cb = 0; cb < 4; ++cb) {
            int nb = cc * 4 + cb;
            #pragma unroll
            for (int ks = 0; ks < 2; ++ks) {
                bf16x8 wf = *(const bf16x8*)(w3f + (size_t)((nb * 2 + ks) * 64 + lane) * 8);
                g1a[0][cb] = MFMA16(xf[0][ks], wf, g1a[0][cb]);
                g1a[1][cb] = MFMA16(xf[1][ks], wf, g1a[1][cb]);
            }
        }
        // epilogue: relu -> packed b64 at permuted slots (chunk-local p = ln*4 + cb)
        #pragma unroll
        for (int rb = 0; rb < 2; ++rb)
            #pragma unroll
            for (int jj = 0; jj < 4; ++jj) {
                int row = rb * 16 + lg * 4 + jj;
                bf16x4 av;
                #pragma unroll
                for (int cb = 0; cb < 4; ++cb)
                    av[cb] = (__bf16)fmaxf(g1a[rb][cb][jj], 0.f);
                *(bf16x4*)&A1[row * XS + ln * 4] = av;
            }
        // GEMM2 partial over this 64-wide chunk
        #pragma unroll
        for (int kb2 = 0; kb2 < 2; ++kb2) {
            bf16x8 a1f[2];
            #pragma unroll
            for (int rb = 0; rb < 2; ++rb)
                a1f[rb] = *(const bf16x8*)&A1[(rb * 16 + ln) * XS + kb2 * 32 + lg * 8];
            #pragma unroll
            for (int nb = 0; nb < 4; ++nb) {
                bf16x8 wf = *(const bf16x8*)(w4f + (size_t)((nb * 8 + cc * 2 + kb2) * 64 + lane) * 8);
                acc2[0][nb] = MFMA16(a1f[0], wf, acc2[0][nb]);
                acc2[1][nb] = MFMA16(a1f[1], wf, acc2[1][nb]);
            }
        }
    }

    // ---------- Phase F: channel softmax (no max-sub: logits O(1), f32-exp exact ratios)
    #pragma unroll
    for (int rb = 0; rb < 2; ++rb) {
        const int nrow = n0 + rb;
        float res[4] = {0.f, 0.f, 0.f, 0.f};
        #pragma unroll
        for (int jj = 0; jj < 4; ++jj) {   // each jj = one neighbor row per lane group
            float e0 = __expf(acc2[rb][0][jj]);
            float e1 = __expf(acc2[rb][1][jj]);
            float e2 = __expf(acc2[rb][2][jj]);
            float e3 = __expf(acc2[rb][3][jj]);
            float s = (e0 + e1) + (e2 + e3);
            #pragma unroll
            for (int d = 1; d < 16; d <<= 1) s += __shfl_xor(s, d, 64);
            float inv = 1.0f / s;
            res[0] = fmaf(e0 * inv, vvv[rb][0] + pacc[rb][0][jj], res[0]);
            res[1] = fmaf(e1 * inv, vvv[rb][1] + pacc[rb][1][jj], res[1]);
            res[2] = fmaf(e2 * inv, vvv[rb][2] + pacc[rb][2][jj], res[2]);
            res[3] = fmaf(e3 * inv, vvv[rb][3] + pacc[rb][3][jj], res[3]);
        }
        #pragma unroll
        for (int nb = 0; nb < 4; ++nb) {   // sum over the 4 lane groups (16 neighbors total)
            res[nb] += __shfl_xor(res[nb], 16, 64);
            res[nb] += __shfl_xor(res[nb], 32, 64);
        }
        float o = (lg == 0) ? res[0] : (lg == 1) ? res[1] : (lg == 2) ? res[2] : res[3];
        out[(b * NN + nrow) * 64 + lane] = o;
    }
}

extern "C" void kernel_launch(void* const* d_in, const int* in_sizes, int n_in,
                              void* d_out, int out_size, void* d_ws, size_t ws_size,
                              hipStream_t stream) {
    const float* key   = (const float*)d_in[0];
    const float* query = (const float*)d_in[1];
    const float* value = (const float*)d_in[2];
    const float* pos   = (const float*)d_in[3];
    const int*   idx   = (const int*)d_in[4];
    const float* W1    = (const float*)d_in[5];
    const float* b1    = (const float*)d_in[6];
    const float* g1    = (const float*)d_in[7];
    const float* bt1   = (const float*)d_in[8];
    const float* W2    = (const float*)d_in[9];
    const float* b2    = (const float*)d_in[10];
    const float* W3    = (const float*)d_in[11];
    const float* b3    = (const float*)d_in[12];
    const float* g3    = (const float*)d_in[13];
    const float* bt3   = (const float*)d_in[14];
    const float* W4    = (const float*)d_in[15];
    const float* b4    = (const float*)d_in[16];
    unsigned char* ws  = (unsigned char*)d_ws;
    float* out = (float*)d_out;

    if (ws_size < WS_NEEDED) return;   // fail cleanly instead of corrupting device memory

    hipLaunchKernelGGL(prep_kernel, dim3(153), dim3(256), 0, stream,
                       W1, b1, g1, bt1, W2, W3, b3, g3, bt3, W4, ws);
    hipLaunchKernelGGL(fused_kernel, dim3(8192), dim3(256), 0, stream,
                       key, query, value, pos, idx, b2, b4, ws, out);
}

// Round 12
// 245.285 us; speedup vs baseline: 1.6802x; 1.0486x over previous
//
#include <hip/hip_runtime.h>
#include <hip/hip_bf16.h>

typedef __bf16 bf16x8 __attribute__((ext_vector_type(8)));
typedef __bf16 bf16x4 __attribute__((ext_vector_type(4)));
typedef float  f32x4  __attribute__((ext_vector_type(4)));

#define MFMA16(A,B,C) __builtin_amdgcn_mfma_f32_16x16x32_bf16((A),(B),(C),0,0,0)

constexpr int NB = 8, NN = 8192, KK = 16;
constexpr int XS = 72;            // LDS row stride (elements): 144B; conflicts measured negligible (1.3us)
constexpr size_t WS_NEEDED = 78848;

// Permuted k-order everywhere (exact): channel c = cb*16+u <-> slot p = u*4+cb.
// ws layout: w3f 32768 @0 | w4f 32768 @32768 | w2f 8192 @65536 | w1f 4096 @73728 | c3f 1024 @77824

__global__ void prep_kernel(const float* __restrict__ W1, const float* __restrict__ b1,
                            const float* __restrict__ g1, const float* __restrict__ bt1,
                            const float* __restrict__ W2, const float* __restrict__ W3,
                            const float* __restrict__ b3, const float* __restrict__ g3,
                            const float* __restrict__ bt3, const float* __restrict__ W4,
                            unsigned char* __restrict__ ws)
{
    __bf16* w3f = (__bf16*)(ws);
    __bf16* w4f = (__bf16*)(ws + 32768);
    __bf16* w2f = (__bf16*)(ws + 65536);
    __bf16* w1f = (__bf16*)(ws + 73728);
    float*  c3f = (float*)(ws + 77824);

    const float inv = 1.0f / sqrtf(1.0f + 1e-3f);   // BN with init moving stats
    int t = blockIdx.x * 256 + threadIdx.x;

    if (t < 16384) {                    // w3f
        int i = t & 7, lane = (t >> 3) & 63, r = t >> 9;
        int ks = r & 1, nb = r >> 1;
        int p = ks * 32 + (lane >> 4) * 8 + i;
        int c = (p & 3) * 16 + (p >> 2);
        int n = nb * 16 + (lane & 15);
        w3f[t] = (__bf16)(W3[c * 256 + n] * (g3[n] * inv));
    } else if (t < 32768) {             // w4f
        int u = t - 16384;
        int i = u & 7, lane = (u >> 3) & 63, r = u >> 9;
        int kb = r & 7, nb = r >> 3;
        int q = (kb & 1) * 32 + (lane >> 4) * 8 + i;
        int c = (kb >> 1) * 64 + (q & 3) * 16 + (q >> 2);
        int n = nb * 16 + (lane & 15);
        w4f[u] = (__bf16)(W4[c * 64 + n] * 0.125f);
    } else if (t < 36864) {             // w2f
        int u = t - 32768;
        int i = u & 7, lane = (u >> 3) & 63, r = u >> 9;
        int ks = r & 1, nb = r >> 1;
        int p = ks * 32 + (lane >> 4) * 8 + i;
        int c = (p & 3) * 16 + (p >> 2);
        int n = nb * 16 + (lane & 15);
        w2f[u] = (__bf16)(W2[c * 64 + n]);
    } else if (t < 38912) {             // w1f (k=3 = BN-folded bias row; A-side supplies 1.0)
        int u = t - 36864;
        int i = u & 7, lane = (u >> 3) & 63, nb = u >> 9;
        int kk = (lane >> 4) * 8 + i;
        int n = nb * 16 + (lane & 15);
        float v = 0.f;
        if (kk < 3)       v = W1[kk * 64 + n] * (g1[n] * inv);
        else if (kk == 3) v = b1[n] * (g1[n] * inv) + bt1[n];
        w1f[u] = (__bf16)v;
    } else if (t < 39168) {             // c3f
        int n = t - 38912;
        c3f[n] = b3[n] * (g3[n] * inv) + bt3[n];
    }
}

// One wave = 2 points. No barriers. Gathers prefetched ahead of the MFMA chain.
// Biases+query folded into MFMA C-in. cc loop: unrolled, ping-pong LDS bounce
// (A1 <-> dead X region) to kill the WAR serialization; setprio around MFMA clusters.
__global__ __launch_bounds__(256, 2) void fused_kernel(
    const float* __restrict__ key, const float* __restrict__ query,
    const float* __restrict__ value, const float* __restrict__ pos,
    const int* __restrict__ idx, const float* __restrict__ b2,
    const float* __restrict__ b4, const unsigned char* __restrict__ ws,
    float* __restrict__ out)
{
    const __bf16* w3f = (const __bf16*)(ws);
    const __bf16* w4f = (const __bf16*)(ws + 32768);
    const __bf16* w2f = (const __bf16*)(ws + 65536);
    const __bf16* w1f = (const __bf16*)(ws + 73728);
    const float*  c3f = (const float*)(ws + 77824);

    const f32x4 ZERO4 = {0.f, 0.f, 0.f, 0.f};

    __shared__ __attribute__((aligned(16))) __bf16 sX [4][32 * XS];  // h, X, then ping-pong buf
    __shared__ __attribute__((aligned(16))) __bf16 sA1[4][32 * XS];  // GEMM1 chunk bounce (pong)

    const int wv   = threadIdx.x >> 6;
    const int lane = threadIdx.x & 63;
    const int lg   = lane >> 4;      // 16-lane group 0..3
    const int ln   = lane & 15;

    const int ptbase = blockIdx.x * 8 + wv * 2;  // global point of rb=0
    const int b  = ptbase >> 13;                 // / 8192
    const int n0 = ptbase & 8191;

    __bf16* X  = sX[wv];
    __bf16* A1 = sA1[wv];

    // ---------- Prefetch wave-local inputs (issue ASAP; consumed much later)
    float qv[2][4], vvv[2][4], b4v[4];
    #pragma unroll
    for (int rb = 0; rb < 2; ++rb)
        #pragma unroll
        for (int cb = 0; cb < 4; ++cb) {
            qv[rb][cb]  = query[(b * NN + n0 + rb) * 64 + cb * 16 + ln];
            vvv[rb][cb] = value[(b * NN + n0 + rb) * 64 + cb * 16 + ln];
        }
    #pragma unroll
    for (int nb = 0; nb < 4; ++nb) b4v[nb] = b4[nb * 16 + ln] * 0.125f;
    float b2v[4];
    #pragma unroll
    for (int cb = 0; cb < 4; ++cb) b2v[cb] = b2[cb * 16 + ln];

    // idx + pos gather (lane<32 covers the 32 rows; row r of point p held by lane p*16+(r&15))
    int   jl = 0;
    float prx = 0.f, pry = 0.f, prz = 0.f;
    if (lane < 32) {
        int p = lane >> 4, k = lane & 15;
        int n = n0 + p;
        jl = idx[(b * NN + n) * KK + k];
        int pb = (b * NN + n) * 3, jb = (b * NN + jl) * 3;
        prx = pos[pb + 0] - pos[jb + 0];
        pry = pos[pb + 1] - pos[jb + 1];
        prz = pos[pb + 2] - pos[jb + 2];
    }

    // key gather prefetch: j via shfl (src lane rb*16+lg*4+jj); ~200cy L2 latency hides
    // under Phase A+B MFMAs.
    float kreg[2][4][4];
    #pragma unroll
    for (int rb = 0; rb < 2; ++rb)
        #pragma unroll
        for (int jj = 0; jj < 4; ++jj) {
            int j = __shfl(jl, rb * 16 + lg * 4 + jj, 64);
            int jb = (b * NN + j) * 64;
            #pragma unroll
            for (int cb = 0; cb < 4; ++cb)
                kreg[rb][jj][cb] = key[jb + cb * 16 + ln];
        }

    // ---------- Phase A: h = relu(PR @ W1f) via MFMA (bias at k=3, A supplies 1.0)
    bf16x8 af[2];
    #pragma unroll
    for (int rb = 0; rb < 2; ++rb) {
        float ax = __shfl(prx, rb * 16 + ln, 64);
        float ay = __shfl(pry, rb * 16 + ln, 64);
        float az = __shfl(prz, rb * 16 + ln, 64);
        bf16x8 a;
        #pragma unroll
        for (int i = 0; i < 8; ++i) a[i] = (__bf16)0.0f;
        if (lg == 0) {
            a[0] = (__bf16)ax; a[1] = (__bf16)ay; a[2] = (__bf16)az;
            a[3] = (__bf16)1.0f;
        }
        af[rb] = a;
    }
    f32x4 pa[2][4];
    #pragma unroll
    for (int nb = 0; nb < 4; ++nb) {
        bf16x8 wf = *(const bf16x8*)(w1f + (size_t)(nb * 64 + lane) * 8);
        pa[0][nb] = MFMA16(af[0], wf, ZERO4);
        pa[1][nb] = MFMA16(af[1], wf, ZERO4);
    }
    // h epilogue: relu -> packed b64 at permuted slots (slot p = ln*4 + nb)
    #pragma unroll
    for (int rb = 0; rb < 2; ++rb)
        #pragma unroll
        for (int jj = 0; jj < 4; ++jj) {
            int row = rb * 16 + lg * 4 + jj;
            bf16x4 hv;
            #pragma unroll
            for (int nb = 0; nb < 4; ++nb) hv[nb] = (__bf16)fmaxf(pa[rb][nb][jj], 0.f);
            *(bf16x4*)&X[row * XS + ln * 4] = hv;
        }

    // ---------- Phase B: pacc = h @ W2f + (b2 + q)   (pacc = posem + q, C-in folded)
    bf16x8 hf[2][2];
    #pragma unroll
    for (int rb = 0; rb < 2; ++rb)
        #pragma unroll
        for (int ks = 0; ks < 2; ++ks)
            hf[rb][ks] = *(const bf16x8*)&X[(rb * 16 + ln) * XS + ks * 32 + lg * 8];
    f32x4 pacc[2][4];
    #pragma unroll
    for (int rb = 0; rb < 2; ++rb)
        #pragma unroll
        for (int cb = 0; cb < 4; ++cb) {
            float c0s = b2v[cb] + qv[rb][cb];
            f32x4 c0 = {c0s, c0s, c0s, c0s};
            pacc[rb][cb] = c0;
        }
    // vvv becomes (v - q); qv dead after this point. Phase F uses vvv + pacc = v + posem.
    #pragma unroll
    for (int rb = 0; rb < 2; ++rb)
        #pragma unroll
        for (int cb = 0; cb < 4; ++cb) vvv[rb][cb] -= qv[rb][cb];
    #pragma unroll
    for (int cb = 0; cb < 4; ++cb)
        #pragma unroll
        for (int ks = 0; ks < 2; ++ks) {
            bf16x8 wf = *(const bf16x8*)(w2f + (size_t)((cb * 2 + ks) * 64 + lane) * 8);
            pacc[0][cb] = MFMA16(hf[0][ks], wf, pacc[0][cb]);
            pacc[1][cb] = MFMA16(hf[1][ks], wf, pacc[1][cb]);
        }

    // X = pacc - key (= q - key + posem), packed write (C-layout: col=ln, row=lg*4+jj)
    #pragma unroll
    for (int rb = 0; rb < 2; ++rb)
        #pragma unroll
        for (int jj = 0; jj < 4; ++jj) {
            int row = rb * 16 + lg * 4 + jj;
            bf16x4 xv;
            #pragma unroll
            for (int cb = 0; cb < 4; ++cb)
                xv[cb] = (__bf16)(pacc[rb][cb][jj] - kreg[rb][jj][cb]);
            *(bf16x4*)&X[row * XS + ln * 4] = xv;
        }

    // ---------- Phase D: A1 = relu(X @ W3f + c3); acc2 += A1 @ W4f  (4 col-chunks of 64)
    // Ping-pong bounce buffer: X region is dead after xf load -> alternate A1/X per cc.
    // Removes the WAR hazard that serialized GEMM1(cc+1) behind GEMM2(cc) reads.
    bf16x8 xf[2][2];
    #pragma unroll
    for (int rb = 0; rb < 2; ++rb)
        #pragma unroll
        for (int ks = 0; ks < 2; ++ks)
            xf[rb][ks] = *(const bf16x8*)&X[(rb * 16 + ln) * XS + ks * 32 + lg * 8];
    f32x4 acc2[2][4];
    #pragma unroll
    for (int rb = 0; rb < 2; ++rb)
        #pragma unroll
        for (int nb = 0; nb < 4; ++nb) {
            f32x4 c0 = {b4v[nb], b4v[nb], b4v[nb], b4v[nb]};
            acc2[rb][nb] = c0;   // b4 folded into GEMM2 C-in
        }

    #pragma unroll
    for (int cc = 0; cc < 4; ++cc) {
        __bf16* BUF = (cc & 1) ? X : A1;   // constant after unroll
        f32x4 g1a[2][4];
        #pragma unroll
        for (int cb = 0; cb < 4; ++cb) {
            float c3v = c3f[(cc * 4 + cb) * 16 + ln];
            f32x4 c0 = {c3v, c3v, c3v, c3v};
            g1a[0][cb] = c0;     // c3 folded into GEMM1 C-in
            g1a[1][cb] = c0;
        }
        __builtin_amdgcn_s_setprio(1);
        #pragma unroll
        for (int cb = 0; cb < 4; ++cb) {
            int nb = cc * 4 + cb;
            #pragma unroll
            for (int ks = 0; ks < 2; ++ks) {
                bf16x8 wf = *(const bf16x8*)(w3f + (size_t)((nb * 2 + ks) * 64 + lane) * 8);
                g1a[0][cb] = MFMA16(xf[0][ks], wf, g1a[0][cb]);
                g1a[1][cb] = MFMA16(xf[1][ks], wf, g1a[1][cb]);
            }
        }
        __builtin_amdgcn_s_setprio(0);
        // epilogue: relu -> packed b64 at permuted slots (chunk-local p = ln*4 + cb)
        #pragma unroll
        for (int rb = 0; rb < 2; ++rb)
            #pragma unroll
            for (int jj = 0; jj < 4; ++jj) {
                int row = rb * 16 + lg * 4 + jj;
                bf16x4 av;
                #pragma unroll
                for (int cb = 0; cb < 4; ++cb)
                    av[cb] = (__bf16)fmaxf(g1a[rb][cb][jj], 0.f);
                *(bf16x4*)&BUF[row * XS + ln * 4] = av;
            }
        // GEMM2 partial over this 64-wide chunk
        #pragma unroll
        for (int kb2 = 0; kb2 < 2; ++kb2) {
            bf16x8 a1f[2];
            #pragma unroll
            for (int rb = 0; rb < 2; ++rb)
                a1f[rb] = *(const bf16x8*)&BUF[(rb * 16 + ln) * XS + kb2 * 32 + lg * 8];
            __builtin_amdgcn_s_setprio(1);
            #pragma unroll
            for (int nb = 0; nb < 4; ++nb) {
                bf16x8 wf = *(const bf16x8*)(w4f + (size_t)((nb * 8 + cc * 2 + kb2) * 64 + lane) * 8);
                acc2[0][nb] = MFMA16(a1f[0], wf, acc2[0][nb]);
                acc2[1][nb] = MFMA16(a1f[1], wf, acc2[1][nb]);
            }
            __builtin_amdgcn_s_setprio(0);
        }
    }

    // ---------- Phase F: channel softmax (no max-sub: logits O(1), f32-exp exact ratios)
    #pragma unroll
    for (int rb = 0; rb < 2; ++rb) {
        const int nrow = n0 + rb;
        float res[4] = {0.f, 0.f, 0.f, 0.f};
        #pragma unroll
        for (int jj = 0; jj < 4; ++jj) {   // each jj = one neighbor row per lane group
            float e0 = __expf(acc2[rb][0][jj]);
            float e1 = __expf(acc2[rb][1][jj]);
            float e2 = __expf(acc2[rb][2][jj]);
            float e3 = __expf(acc2[rb][3][jj]);
            float s = (e0 + e1) + (e2 + e3);
            #pragma unroll
            for (int d = 1; d < 16; d <<= 1) s += __shfl_xor(s, d, 64);
            float inv = 1.0f / s;
            res[0] = fmaf(e0 * inv, vvv[rb][0] + pacc[rb][0][jj], res[0]);
            res[1] = fmaf(e1 * inv, vvv[rb][1] + pacc[rb][1][jj], res[1]);
            res[2] = fmaf(e2 * inv, vvv[rb][2] + pacc[rb][2][jj], res[2]);
            res[3] = fmaf(e3 * inv, vvv[rb][3] + pacc[rb][3][jj], res[3]);
        }
        #pragma unroll
        for (int nb = 0; nb < 4; ++nb) {   // sum over the 4 lane groups (16 neighbors total)
            res[nb] += __shfl_xor(res[nb], 16, 64);
            res[nb] += __shfl_xor(res[nb], 32, 64);
        }
        float o = (lg == 0) ? res[0] : (lg == 1) ? res[1] : (lg == 2) ? res[2] : res[3];
        out[(b * NN + nrow) * 64 + lane] = o;
    }
}

extern "C" void kernel_launch(void* const* d_in, const int* in_sizes, int n_in,
                              void* d_out, int out_size, void* d_ws, size_t ws_size,
                              hipStream_t stream) {
    const float* key   = (const float*)d_in[0];
    const float* query = (const float*)d_in[1];
    const float* value = (const float*)d_in[2];
    const float* pos   = (const float*)d_in[3];
    const int*   idx   = (const int*)d_in[4];
    const float* W1    = (const float*)d_in[5];
    const float* b1    = (const float*)d_in[6];
    const float* g1    = (const float*)d_in[7];
    const float* bt1   = (const float*)d_in[8];
    const float* W2    = (const float*)d_in[9];
    const float* b2    = (const float*)d_in[10];
    const float* W3    = (const float*)d_in[11];
    const float* b3    = (const float*)d_in[12];
    const float* g3    = (const float*)d_in[13];
    const float* bt3   = (const float*)d_in[14];
    const float* W4    = (const float*)d_in[15];
    const float* b4    = (const float*)d_in[16];
    unsigned char* ws  = (unsigned char*)d_ws;
    float* out = (float*)d_out;

    if (ws_size < WS_NEEDED) return;   // fail cleanly instead of corrupting device memory

    hipLaunchKernelGGL(prep_kernel, dim3(153), dim3(256), 0, stream,
                       W1, b1, g1, bt1, W2, W3, b3, g3, bt3, W4, ws);
    hipLaunchKernelGGL(fused_kernel, dim3(8192), dim3(256), 0, stream,
                       key, query, value, pos, idx, b2, b4, ws, out);
}